// Round 1
// baseline (459.995 us; speedup 1.0000x reference)
//
#include <hip/hip_runtime.h>
#include <stdint.h>

// ---- problem constants ----
#define BT   6272      // B*T = 32*196
#define LAT  256
#define NJ3  13
#define NJ2  10
#define NJ1  20
#define NJ   43
#define D3   39
#define D2   20
#define XDIM 79        // D3+D2+D1
#define OUTROW 11008   // NJ*LAT

typedef _Float16 half8  __attribute__((ext_vector_type(8)));
typedef _Float16 half4v __attribute__((ext_vector_type(4)));
typedef float    floatx4 __attribute__((ext_vector_type(4)));

// tanh-approx gelu (matches jax.nn.gelu default approximate=True)
// gelu(h) = 0.5h(1+tanh(u)), u = 0.7978845608(h + 0.044715 h^3)
// tanh(u) = 1 - 2/(exp(2u)+1)  ->  gelu = h*(1 - r), r = 1/(exp(2u)+1)
__device__ __forceinline__ float fast_gelu(float h) {
    float p  = h * h;
    float u2 = h * (1.5957691216057308f + 0.0713548162f * p); // 2u
    float e  = __expf(u2);
    float r  = __builtin_amdgcn_rcpf(e + 1.0f);
    return h - h * r;
}

// ---- pre-pass: W2[j][l][m] (fp32) -> W2t[j][m][l] (f16), per 64x64 tile ----
__global__ __launch_bounds__(256) void transpose_w2(
    const float* __restrict__ W2_3, const float* __restrict__ W2_2,
    const float* __restrict__ W2_1, _Float16* __restrict__ W2t)
{
    __shared__ float tile[64][65];
    const int bid = blockIdx.x;
    const int j   = bid >> 4;          // 16 tiles per joint
    const int t   = bid & 15;
    const int l0  = (t >> 2) * 64;
    const int m0  = (t & 3) * 64;

    const float* W2 = (j < NJ3) ? (W2_3 + (size_t)j * 65536)
                    : (j < NJ3 + NJ2) ? (W2_2 + (size_t)(j - NJ3) * 65536)
                    : (W2_1 + (size_t)(j - NJ3 - NJ2) * 65536);

    const int tx = threadIdx.x & 15, ty = threadIdx.x >> 4;
#pragma unroll
    for (int rr = 0; rr < 4; ++rr) {
        const int row = ty + rr * 16;
        const float4 v = *(const float4*)(W2 + (size_t)(l0 + row) * 256 + m0 + tx * 4);
        tile[row][tx * 4 + 0] = v.x;
        tile[row][tx * 4 + 1] = v.y;
        tile[row][tx * 4 + 2] = v.z;
        tile[row][tx * 4 + 3] = v.w;
    }
    __syncthreads();
#pragma unroll
    for (int rr = 0; rr < 4; ++rr) {
        const int mrow = ty + rr * 16;
        const int ll   = tx * 4;
        half4v o;
        o[0] = (_Float16)tile[ll + 0][mrow];
        o[1] = (_Float16)tile[ll + 1][mrow];
        o[2] = (_Float16)tile[ll + 2][mrow];
        o[3] = (_Float16)tile[ll + 3][mrow];
        *(half4v*)(W2t + ((size_t)j * 256 + m0 + mrow) * 256 + l0 + ll) = o;
    }
}

// ---- fused main kernel: per block = (joint j, 64-row tile) ----
// 4 waves = 1(M) x 4(N); each wave: 4x4 tiles of 16x16, K-chunks of 64.
// A (=gelu(x W1 + b1) in f16) is built in LDS in fragment-ready lane-linear
// layout: slot (i, kk2, lane) holds 16B so a-frag read = ds_read_b128 at
// base + lane*16 (conflict-free minimum phases).
__global__ __launch_bounds__(256, 4) void motion_main(
    const float* __restrict__ x,
    const float* __restrict__ W1_3, const float* __restrict__ b1_3, const float* __restrict__ b2_3,
    const float* __restrict__ W1_2, const float* __restrict__ b1_2, const float* __restrict__ b2_2,
    const float* __restrict__ W1_1, const float* __restrict__ b1_1, const float* __restrict__ b2_1,
    const _Float16* __restrict__ W2t,
    float* __restrict__ out)
{
    __shared__ half8 Alds[512];        // [i(4)][kk2(2)][lane(64)] x 16B = 8 KB

    const int bid = blockIdx.x;
    const int j   = bid / 98;          // m-tile fastest -> consecutive blocks share W2t[j] in L2
    const int mt  = bid % 98;
    const int r0  = mt * 64;

    int d, xoff;
    const float *W1, *b1, *b2;
    if (j < NJ3)            { d = 3; xoff = j * 3;
                              W1 = W1_3 + j * 768;  b1 = b1_3 + j * 256;  b2 = b2_3 + j * 256; }
    else if (j < NJ3 + NJ2) { const int q = j - NJ3; d = 2; xoff = D3 + q * 2;
                              W1 = W1_2 + q * 512;  b1 = b1_2 + q * 256;  b2 = b2_2 + q * 256; }
    else                    { const int q = j - NJ3 - NJ2; d = 1; xoff = D3 + D2 + q;
                              W1 = W1_1 + q * 256;  b1 = b1_1 + q * 256;  b2 = b2_1 + q * 256; }

    const int tid  = threadIdx.x;
    const int rr   = tid >> 2;         // 0..63: row within the 64-row tile (h-compute role)
    const int qq   = tid & 3;          // l-quarter within chunk
    const int lane = tid & 63;
    const int wv   = tid >> 6;         // wave id 0..3 -> 64-wide N slice
    const int m16  = lane & 15;
    const int quad = lane >> 4;

    // this thread's x row stays in registers for the whole kernel
    const float* xr = x + (size_t)(r0 + rr) * XDIM + xoff;
    const float xv0 = xr[0];
    const float xv1 = (d > 1) ? xr[1] : 0.0f;
    const float xv2 = (d > 2) ? xr[2] : 0.0f;

    floatx4 acc[4][4];
#pragma unroll
    for (int i = 0; i < 4; ++i)
#pragma unroll
        for (int jj = 0; jj < 4; ++jj)
            acc[i][jj] = (floatx4){0.f, 0.f, 0.f, 0.f};

    const _Float16* W2j = W2t + (size_t)j * 65536 + (size_t)(wv * 64) * 256;

    for (int kc = 0; kc < 4; ++kc) {
        __syncthreads();               // previous chunk's frag reads done before overwrite
        // ---- h-compute: rows rr, l = kc*64 + c*8 .. +8, c = qq*2+run ----
#pragma unroll
        for (int run = 0; run < 2; ++run) {
            const int c  = qq * 2 + run;           // 0..7: 8-wide l block in chunk
            const int l0 = kc * 64 + c * 8;
            float h[8];
#pragma unroll
            for (int u = 0; u < 8; ++u) h[u] = b1[l0 + u];
#pragma unroll
            for (int u = 0; u < 8; ++u) h[u] += xv0 * W1[l0 + u];
            if (d > 1) {
#pragma unroll
                for (int u = 0; u < 8; ++u) h[u] += xv1 * W1[256 + l0 + u];
            }
            if (d > 2) {
#pragma unroll
                for (int u = 0; u < 8; ++u) h[u] += xv2 * W1[512 + l0 + u];
            }
            half8 v;
#pragma unroll
            for (int u = 0; u < 8; ++u) v[u] = (_Float16)fast_gelu(h[u]);
            // slot: i = rr>>4, kk2 = c>>2, quad_t = c&3, m_t = rr&15
            Alds[(((rr >> 4) * 2 + (c >> 2)) * 4 + (c & 3)) * 16 + (rr & 15)] = v;
        }
        __syncthreads();
        // ---- MFMA over the chunk ----
#pragma unroll
        for (int kk2 = 0; kk2 < 2; ++kk2) {
            half8 af[4];
#pragma unroll
            for (int i = 0; i < 4; ++i) af[i] = Alds[(i * 2 + kk2) * 64 + lane];
            const int kidx = kc * 64 + kk2 * 32 + quad * 8;
#pragma unroll
            for (int jj = 0; jj < 4; ++jj) {
                const half8 bf = *(const half8*)(W2j + (size_t)(jj * 16 + m16) * 256 + kidx);
#pragma unroll
                for (int i = 0; i < 4; ++i)
                    acc[i][jj] = __builtin_amdgcn_mfma_f32_16x16x32_f16(af[i], bf, acc[i][jj], 0, 0, 0);
            }
        }
    }

    // ---- epilogue: +b2, store fp32 (C/D layout: col=lane&15, row=quad*4+reg) ----
#pragma unroll
    for (int jj = 0; jj < 4; ++jj) {
        const int n   = wv * 64 + jj * 16 + m16;
        const float b2v = b2[n];
#pragma unroll
        for (int i = 0; i < 4; ++i) {
            const int rbase = r0 + i * 16 + quad * 4;
            float* op = out + (size_t)rbase * OUTROW + (size_t)j * 256 + n;
#pragma unroll
            for (int g = 0; g < 4; ++g)
                op[(size_t)g * OUTROW] = acc[i][jj][g] + b2v;
        }
    }
}

extern "C" void kernel_launch(void* const* d_in, const int* in_sizes, int n_in,
                              void* d_out, int out_size, void* d_ws, size_t ws_size,
                              hipStream_t stream) {
    const float* x    = (const float*)d_in[0];
    const float* W1_3 = (const float*)d_in[1];
    const float* b1_3 = (const float*)d_in[2];
    const float* W2_3 = (const float*)d_in[3];
    const float* b2_3 = (const float*)d_in[4];
    const float* W1_2 = (const float*)d_in[5];
    const float* b1_2 = (const float*)d_in[6];
    const float* W2_2 = (const float*)d_in[7];
    const float* b2_2 = (const float*)d_in[8];
    const float* W1_1 = (const float*)d_in[9];
    const float* b1_1 = (const float*)d_in[10];
    const float* W2_1 = (const float*)d_in[11];
    const float* b2_1 = (const float*)d_in[12];
    float* out = (float*)d_out;
    _Float16* W2t = (_Float16*)d_ws;   // 43*256*256 f16 = 5.64 MB, rebuilt every call

    transpose_w2<<<NJ * 16, 256, 0, stream>>>(W2_3, W2_2, W2_1, W2t);
    motion_main<<<NJ * 98, 256, 0, stream>>>(x, W1_3, b1_3, b2_3,
                                             W1_2, b1_2, b2_2,
                                             W1_1, b1_1, b2_1, W2t, out);
}

// Round 2
// 455.852 us; speedup vs baseline: 1.0091x; 1.0091x over previous
//
#include <hip/hip_runtime.h>
#include <stdint.h>

// ---- problem constants ----
#define BT   6272      // B*T = 32*196
#define LAT  256
#define NJ3  13
#define NJ2  10
#define NJ1  20
#define NJ   43
#define D3   39
#define D2   20
#define XDIM 79        // D3+D2+D1
#define OUTROW 11008   // NJ*LAT

typedef _Float16 half8  __attribute__((ext_vector_type(8)));
typedef _Float16 half4v __attribute__((ext_vector_type(4)));
typedef float    floatx4 __attribute__((ext_vector_type(4)));

// tanh-approx gelu (matches jax.nn.gelu default approximate=True)
// gelu(h) = h - h/(exp(2u)+1), 2u = h*(1.5957691 + 0.0713548*h^2)
__device__ __forceinline__ float fast_gelu(float h) {
    float p  = h * h;
    float u2 = h * (1.5957691216057308f + 0.0713548162f * p);
    float e  = __expf(u2);
    float r  = __builtin_amdgcn_rcpf(e + 1.0f);
    return h - h * r;
}

// ---- pre-pass: W2[j][l][m] (fp32) -> W2t[j][m][l] (f16), per 64x64 tile ----
__global__ __launch_bounds__(256) void transpose_w2(
    const float* __restrict__ W2_3, const float* __restrict__ W2_2,
    const float* __restrict__ W2_1, _Float16* __restrict__ W2t)
{
    __shared__ float tile[64][65];
    const int bid = blockIdx.x;
    const int j   = bid >> 4;          // 16 tiles per joint
    const int t   = bid & 15;
    const int l0  = (t >> 2) * 64;
    const int m0  = (t & 3) * 64;

    const float* W2 = (j < NJ3) ? (W2_3 + (size_t)j * 65536)
                    : (j < NJ3 + NJ2) ? (W2_2 + (size_t)(j - NJ3) * 65536)
                    : (W2_1 + (size_t)(j - NJ3 - NJ2) * 65536);

    const int tx = threadIdx.x & 15, ty = threadIdx.x >> 4;
#pragma unroll
    for (int rr = 0; rr < 4; ++rr) {
        const int row = ty + rr * 16;
        const float4 v = *(const float4*)(W2 + (size_t)(l0 + row) * 256 + m0 + tx * 4);
        tile[row][tx * 4 + 0] = v.x;
        tile[row][tx * 4 + 1] = v.y;
        tile[row][tx * 4 + 2] = v.z;
        tile[row][tx * 4 + 3] = v.w;
    }
    __syncthreads();
#pragma unroll
    for (int rr = 0; rr < 4; ++rr) {
        const int mrow = ty + rr * 16;
        const int ll   = tx * 4;
        half4v o;
        o[0] = (_Float16)tile[ll + 0][mrow];
        o[1] = (_Float16)tile[ll + 1][mrow];
        o[2] = (_Float16)tile[ll + 2][mrow];
        o[3] = (_Float16)tile[ll + 3][mrow];
        *(half4v*)(W2t + ((size_t)j * 256 + m0 + mrow) * 256 + l0 + ll) = o;
    }
}

// ---- fused main kernel: per block = (joint j, 64-row tile) ----
// 4 waves = 1(M) x 4(N); each wave: 4x4 tiles of 16x16, K-chunks of 64.
// A (=gelu(x W1 + b1) in f16) is staged in LDS in fragment-ready layout.
// XOR swizzle (m ^ ((slot&3)<<1)) breaks the structural 8-way bank conflict:
// bank group depends only on m16 (slot*64 % 32 == 0), so {m16, m16+8} x quad
// collided 8-way; after swizzle reads are 2-way (free per m136).
// __launch_bounds__(256,3): VGPR cap ~168 (acc 64 + frags + pipeline fits),
// 3 blocks/CU. (256,4) capped at 128 -> acc spills to scratch, ~3x slower.
__global__ __launch_bounds__(256, 3) void motion_main(
    const float* __restrict__ x,
    const float* __restrict__ W1_3, const float* __restrict__ b1_3, const float* __restrict__ b2_3,
    const float* __restrict__ W1_2, const float* __restrict__ b1_2, const float* __restrict__ b2_2,
    const float* __restrict__ W1_1, const float* __restrict__ b1_1, const float* __restrict__ b2_1,
    const _Float16* __restrict__ W2t,
    float* __restrict__ out)
{
    __shared__ half8 Alds[512];        // [slot(32)][m(16)] x 16B = 8 KB

    const int bid = blockIdx.x;
    const int j   = bid / 98;          // m-tile fastest -> consecutive blocks share W2t[j] in L2
    const int mt  = bid % 98;
    const int r0  = mt * 64;

    int d, xoff;
    const float *W1, *b1, *b2;
    if (j < NJ3)            { d = 3; xoff = j * 3;
                              W1 = W1_3 + j * 768;  b1 = b1_3 + j * 256;  b2 = b2_3 + j * 256; }
    else if (j < NJ3 + NJ2) { const int q = j - NJ3; d = 2; xoff = D3 + q * 2;
                              W1 = W1_2 + q * 512;  b1 = b1_2 + q * 256;  b2 = b2_2 + q * 256; }
    else                    { const int q = j - NJ3 - NJ2; d = 1; xoff = D3 + D2 + q;
                              W1 = W1_1 + q * 256;  b1 = b1_1 + q * 256;  b2 = b2_1 + q * 256; }

    const int tid  = threadIdx.x;
    const int rr   = tid >> 2;         // 0..63: row within the 64-row tile (h-compute role)
    const int qq   = tid & 3;          // l-quarter within chunk
    const int lane = tid & 63;
    const int wv   = tid >> 6;         // wave id 0..3 -> 64-wide N slice
    const int m16  = lane & 15;
    const int quad = lane >> 4;

    // this thread's x row stays in registers for the whole kernel
    const float* xr = x + (size_t)(r0 + rr) * XDIM + xoff;
    const float xv0 = xr[0];
    const float xv1 = (d > 1) ? xr[1] : 0.0f;
    const float xv2 = (d > 2) ? xr[2] : 0.0f;

    floatx4 acc[4][4];
#pragma unroll
    for (int i = 0; i < 4; ++i)
#pragma unroll
        for (int jj = 0; jj < 4; ++jj)
            acc[i][jj] = (floatx4){0.f, 0.f, 0.f, 0.f};

    const _Float16* W2j = W2t + (size_t)j * 65536 + (size_t)(wv * 64) * 256;

    for (int kc = 0; kc < 4; ++kc) {
        __syncthreads();               // previous chunk's frag reads done before overwrite
        // ---- h-compute: rows rr, l = kc*64 + c*8 .. +8, c = qq*2+run ----
#pragma unroll
        for (int run = 0; run < 2; ++run) {
            const int c  = qq * 2 + run;           // 0..7: 8-wide l block in chunk
            const int l0 = kc * 64 + c * 8;
            float h[8];
#pragma unroll
            for (int u = 0; u < 8; ++u) h[u] = b1[l0 + u];
#pragma unroll
            for (int u = 0; u < 8; ++u) h[u] += xv0 * W1[l0 + u];
            if (d > 1) {
#pragma unroll
                for (int u = 0; u < 8; ++u) h[u] += xv1 * W1[256 + l0 + u];
            }
            if (d > 2) {
#pragma unroll
                for (int u = 0; u < 8; ++u) h[u] += xv2 * W1[512 + l0 + u];
            }
            half8 v;
#pragma unroll
            for (int u = 0; u < 8; ++u) v[u] = (_Float16)fast_gelu(h[u]);
            // slot = [i(rr>>4)][kk2(c>>2)][quad_t(c&3)], m = rr&15, XOR swizzle on m
            const int slot = (((rr >> 4) * 2 + (c >> 2)) * 4 + (c & 3));
            Alds[slot * 16 + ((rr & 15) ^ ((slot & 3) << 1))] = v;
        }
        __syncthreads();
        // ---- MFMA over the chunk ----
#pragma unroll
        for (int kk2 = 0; kk2 < 2; ++kk2) {
            half8 af[4];
#pragma unroll
            for (int i = 0; i < 4; ++i) {
                const int slot = (i * 2 + kk2) * 4 + quad;
                af[i] = Alds[slot * 16 + (m16 ^ ((slot & 3) << 1))];
            }
            const int kidx = kc * 64 + kk2 * 32 + quad * 8;
#pragma unroll
            for (int jj = 0; jj < 4; ++jj) {
                const half8 bf = *(const half8*)(W2j + (size_t)(jj * 16 + m16) * 256 + kidx);
#pragma unroll
                for (int i = 0; i < 4; ++i)
                    acc[i][jj] = __builtin_amdgcn_mfma_f32_16x16x32_f16(af[i], bf, acc[i][jj], 0, 0, 0);
            }
        }
    }

    // ---- epilogue: +b2, store fp32 (C/D layout: col=lane&15, row=quad*4+reg) ----
#pragma unroll
    for (int jj = 0; jj < 4; ++jj) {
        const int n   = wv * 64 + jj * 16 + m16;
        const float b2v = b2[n];
#pragma unroll
        for (int i = 0; i < 4; ++i) {
            const int rbase = r0 + i * 16 + quad * 4;
            float* op = out + (size_t)rbase * OUTROW + (size_t)j * 256 + n;
#pragma unroll
            for (int g = 0; g < 4; ++g)
                op[(size_t)g * OUTROW] = acc[i][jj][g] + b2v;
        }
    }
}

extern "C" void kernel_launch(void* const* d_in, const int* in_sizes, int n_in,
                              void* d_out, int out_size, void* d_ws, size_t ws_size,
                              hipStream_t stream) {
    const float* x    = (const float*)d_in[0];
    const float* W1_3 = (const float*)d_in[1];
    const float* b1_3 = (const float*)d_in[2];
    const float* W2_3 = (const float*)d_in[3];
    const float* b2_3 = (const float*)d_in[4];
    const float* W1_2 = (const float*)d_in[5];
    const float* b1_2 = (const float*)d_in[6];
    const float* W2_2 = (const float*)d_in[7];
    const float* b2_2 = (const float*)d_in[8];
    const float* W1_1 = (const float*)d_in[9];
    const float* b1_1 = (const float*)d_in[10];
    const float* W2_1 = (const float*)d_in[11];
    const float* b2_1 = (const float*)d_in[12];
    float* out = (float*)d_out;
    _Float16* W2t = (_Float16*)d_ws;   // 43*256*256 f16 = 5.64 MB, rebuilt every call

    transpose_w2<<<NJ * 16, 256, 0, stream>>>(W2_3, W2_2, W2_1, W2t);
    motion_main<<<NJ * 98, 256, 0, stream>>>(x, W1_3, b1_3, b2_3,
                                             W1_2, b1_2, b2_2,
                                             W1_1, b1_1, b2_1, W2t, out);
}